// Round 2
// baseline (110.169 us; speedup 1.0000x reference)
//
#include <hip/hip_runtime.h>
#include <float.h>

#define W   128
#define NB  50
#define GC  64   // columns of G materialized per pass (2 passes); keeps LDS at 23.5 KB -> 6 blocks/CU

typedef float f32x4 __attribute__((ext_vector_type(4)));   // native vector: valid for nontemporal builtin

__global__ __launch_bounds__(256) void mtf_kernel(const float* __restrict__ X,
                                                  float* __restrict__ out) {
    __shared__ int   bins[W];
    __shared__ int   hist[NB * NB];
    __shared__ int   rowsum[NB];
    __shared__ float G[NB][GC];          // G[b][c] = probs[b][bins[C0+c]]
    __shared__ float redmin[4], redmax[4];

    const int tid = threadIdx.x;
    const int s   = blockIdx.x;
    const float* xrow = X + (size_t)s * W;

    // ---- Phase 1: load + min/max reduction (wave = 64 lanes) ----
    float v = 0.0f;
    float vmin = FLT_MAX, vmax = -FLT_MAX;
    if (tid < W) { v = xrow[tid]; vmin = v; vmax = v; }
    #pragma unroll
    for (int off = 32; off >= 1; off >>= 1) {
        vmin = fminf(vmin, __shfl_down(vmin, off, 64));
        vmax = fmaxf(vmax, __shfl_down(vmax, off, 64));
    }
    if ((tid & 63) == 0) { redmin[tid >> 6] = vmin; redmax[tid >> 6] = vmax; }

    // zero histogram + rowsums while reduction lands
    for (int i = tid; i < NB * NB; i += 256) hist[i] = 0;
    if (tid < NB) rowsum[tid] = 0;
    __syncthreads();

    const float mn = fminf(fminf(redmin[0], redmin[1]), fminf(redmin[2], redmin[3]));
    const float mx = fmaxf(fmaxf(redmax[0], redmax[1]), fmaxf(redmax[2], redmax[3]));
    const float d  = (mx - mn) + 1e-6f;   // matches (X_max - X_min + EPS) in fp32

    // ---- Phase 2: bucketize (searchsorted side='left': #{edge < x}) ----
    if (tid < W) {
        float q   = (v - mn) / d;
        float xsc = q * 2.0f - 1.0f;
        double xd = (double)xsc;
        int b = 0;
        #pragma unroll
        for (int k = 1; k <= NB - 1; ++k) {
            double bk = -1.0 + 0.04 * (double)k;   // linspace inner edges (fp64)
            b += (bk < xd) ? 1 : 0;
        }
        bins[tid] = b;
    }
    __syncthreads();

    // Register-cache the 8 row-bins this thread needs in phase 5b (static
    // indices via full unroll -> stays in VGPRs; same rows in both passes).
    const int r0 = tid >> 4;             // 0..15
    const int cc = (tid & 15) * 4;       // 0,4,...,60
    int rbrow[8];
    #pragma unroll
    for (int it = 0; it < 8; ++it) rbrow[it] = bins[r0 + it * 16];

    // ---- Phase 3: transition histogram + row sums (LDS atomics) ----
    if (tid < W - 1) {
        int bi = bins[tid], bj = bins[tid + 1];
        atomicAdd(&hist[bi * NB + bj], 1);
        atomicAdd(&rowsum[bi], 1);
    }
    __syncthreads();

    float* orow = out + (size_t)s * W * W;

    #pragma unroll
    for (int p = 0; p < 2; ++p) {
        const int C0 = p * GC;

        // ---- Phase 5a: materialize G[b][c] = hist[b][bins[C0+c]] / rowsum[b] ----
        // Exact IEEE fp32 division with the same operands as the reference's
        // row-normalize -> bit-identical probs (absmax stays 0).
        // Per wave: b uniform, bins[] read is 2-way (free); only the hist
        // gather is data-dependent (6400/block vs 16384 before).
        for (int i = tid; i < NB * GC; i += 256) {
            int b  = i >> 6;             // 0..49, uniform within a wave
            int c  = i & (GC - 1);
            int rs = rowsum[b];          // broadcast
            G[b][c] = (float)hist[b * NB + bins[C0 + c]]
                    / (float)(rs == 0 ? 1 : rs);
        }
        __syncthreads();

        // ---- Phase 5b: row copy — conflict-free ds_read_b128 + nt store ----
        // Quarter-wave (16 lanes) reads one full 256B G row: lane l covers
        // banks 4l..4l+3, 2 words/bank -> standard full-BW b128 pattern.
        #pragma unroll
        for (int it = 0; it < 8; ++it) {
            int r = r0 + it * 16;
            f32x4 o = *(const f32x4*)&G[rbrow[it]][cc];
            __builtin_nontemporal_store(o, (f32x4*)(orow + r * W + C0 + cc));
        }
        if (p == 0) __syncthreads();     // G reused by pass 1
    }
}

extern "C" void kernel_launch(void* const* d_in, const int* in_sizes, int n_in,
                              void* d_out, int out_size, void* d_ws, size_t ws_size,
                              hipStream_t stream) {
    const float* X = (const float*)d_in[0];
    float* out = (float*)d_out;
    int S = in_sizes[0] / W;             // 256*6 = 1536 series
    mtf_kernel<<<dim3(S), dim3(256), 0, stream>>>(X, out);
}

// Round 3
// 104.930 us; speedup vs baseline: 1.0499x; 1.0499x over previous
//
#include <hip/hip_runtime.h>
#include <float.h>

#define W  128
#define NB 50

__global__ __launch_bounds__(256) void mtf_kernel(const float* __restrict__ X,
                                                  float* __restrict__ out) {
    __shared__ int   bins[W];
    __shared__ int   hist[NB * NB];
    __shared__ int   rowsum[NB];
    __shared__ float probs[NB * NB];
    __shared__ float redmin[4], redmax[4];

    const int tid = threadIdx.x;
    const int s   = blockIdx.x;
    const float* xrow = X + (size_t)s * W;

    // ---- Phase 1: load + min/max reduction (wave = 64 lanes) ----
    float v = 0.0f;
    float vmin = FLT_MAX, vmax = -FLT_MAX;
    if (tid < W) { v = xrow[tid]; vmin = v; vmax = v; }
    #pragma unroll
    for (int off = 32; off >= 1; off >>= 1) {
        vmin = fminf(vmin, __shfl_down(vmin, off, 64));
        vmax = fmaxf(vmax, __shfl_down(vmax, off, 64));
    }
    if ((tid & 63) == 0) { redmin[tid >> 6] = vmin; redmax[tid >> 6] = vmax; }

    // zero histogram + rowsums while reduction lands
    for (int i = tid; i < NB * NB; i += 256) hist[i] = 0;
    if (tid < NB) rowsum[tid] = 0;
    __syncthreads();

    const float mn = fminf(fminf(redmin[0], redmin[1]), fminf(redmin[2], redmin[3]));
    const float mx = fmaxf(fmaxf(redmax[0], redmax[1]), fmaxf(redmax[2], redmax[3]));
    const float d  = (mx - mn) + 1e-6f;   // matches (X_max - X_min + EPS) in fp32

    // ---- Phase 2: bucketize (searchsorted side='left': #{edge < x}) ----
    if (tid < W) {
        float q   = (v - mn) / d;
        float xsc = q * 2.0f - 1.0f;
        double xd = (double)xsc;
        int b = 0;
        #pragma unroll
        for (int k = 1; k <= NB - 1; ++k) {
            double bk = -1.0 + 0.04 * (double)k;   // linspace inner edges (fp64)
            b += (bk < xd) ? 1 : 0;
        }
        bins[tid] = b;
    }
    __syncthreads();

    // ---- Phase 3: transition histogram + row sums (LDS atomics) ----
    if (tid < W - 1) {
        int bi = bins[tid], bj = bins[tid + 1];
        atomicAdd(&hist[bi * NB + bj], 1);
        atomicAdd(&rowsum[bi], 1);
    }
    __syncthreads();

    // ---- Phase 4: row-normalize (exact fp32 division, empty-row guard) ----
    for (int i = tid; i < NB * NB; i += 256) {
        int rs = rowsum[i / NB];
        probs[i] = (float)hist[i] / (float)(rs == 0 ? 1 : rs);
    }
    __syncthreads();

    // ---- Phase 5: gather + contiguous ascending stores ----
    // Wave w owns rows [32w, 32w+32) and writes them in ascending address
    // order: each iteration the 64 lanes emit ONE contiguous 1KB chunk
    // (half-wave = one 512B row), so each CU sustains 24 long sequential
    // HBM write streams instead of 24 strided 4KB-apart streams.
    float* orow = out + (size_t)s * W * W;
    const int wv   = tid >> 6;           // wave 0..3
    const int lane = tid & 63;
    const int c4   = (lane & 31) * 4;    // column chunk within a row
    const int half = lane >> 5;          // which of the 2 rows this iter
    const int b0 = bins[c4], b1 = bins[c4 + 1], b2 = bins[c4 + 2], b3 = bins[c4 + 3];
    #pragma unroll
    for (int it = 0; it < 16; ++it) {
        int row = (wv << 5) + (it << 1) + half;
        int rb  = bins[row] * NB;        // LDS broadcast per half-wave
        float4 o;
        o.x = probs[rb + b0];
        o.y = probs[rb + b1];
        o.z = probs[rb + b2];
        o.w = probs[rb + b3];
        *(float4*)(orow + row * W + c4) = o;
    }
}

extern "C" void kernel_launch(void* const* d_in, const int* in_sizes, int n_in,
                              void* d_out, int out_size, void* d_ws, size_t ws_size,
                              hipStream_t stream) {
    const float* X = (const float*)d_in[0];
    float* out = (float*)d_out;
    int S = in_sizes[0] / W;             // 256*6 = 1536 series
    mtf_kernel<<<dim3(S), dim3(256), 0, stream>>>(X, out);
}